// Round 3
// baseline (5243.351 us; speedup 1.0000x reference)
//
#include <hip/hip_runtime.h>
#include <hip/hip_bf16.h>

#define B_    256
#define S_    512
#define OBS_  64
#define ZD_   16
#define HID_  256
#define ITERS_ 4

// ---------------------------------------------------------------------------
// Encoder: h1 = relu(s0@enc_w1+b1); h2 = relu(h1@enc_w2+b2);
// mu = h2@zmu_w+b; std = exp(clip(h2@zls_w+b,-4,2)); best_score = -inf
// One workgroup per batch row.
// ---------------------------------------------------------------------------
__global__ __launch_bounds__(256) void enc_kernel(
    const float* __restrict__ s0,
    const float* __restrict__ w1, const float* __restrict__ b1,
    const float* __restrict__ w2, const float* __restrict__ b2,
    const float* __restrict__ zmw, const float* __restrict__ zmb,
    const float* __restrict__ zlw, const float* __restrict__ zlb,
    float* __restrict__ mu, float* __restrict__ stdv, float* __restrict__ bscore)
{
    __shared__ float s0s[OBS_];
    __shared__ float h1[HID_];
    __shared__ float h2[HID_];
    const int b = blockIdx.x, tid = threadIdx.x;
    if (tid < OBS_) s0s[tid] = s0[b * OBS_ + tid];
    __syncthreads();
    float a = b1[tid];
    for (int k = 0; k < OBS_; ++k) a = fmaf(s0s[k], w1[k * HID_ + tid], a);
    h1[tid] = fmaxf(a, 0.f);
    __syncthreads();
    float a2 = b2[tid];
    for (int k = 0; k < HID_; ++k) a2 = fmaf(h1[k], w2[k * HID_ + tid], a2);
    h2[tid] = fmaxf(a2, 0.f);
    __syncthreads();
    if (tid < ZD_) {
        float m = zmb[tid];
        for (int k = 0; k < HID_; ++k) m = fmaf(h2[k], zmw[k * ZD_ + tid], m);
        mu[b * ZD_ + tid] = m;
    } else if (tid < 2 * ZD_) {
        const int d = tid - ZD_;
        float l = zlb[d];
        for (int k = 0; k < HID_; ++k) l = fmaf(h2[k], zlw[k * ZD_ + d], l);
        l = fminf(fmaxf(l, -4.f), 2.f);
        stdv[b * ZD_ + d] = expf(l);
    } else if (tid == 2 * ZD_) {
        bscore[b] = -INFINITY;
    }
}

// ---------------------------------------------------------------------------
// Fused K x 256 GEMM + bias + relu on a 32-row tile held transposed in LDS.
// inT:  [K][32]  (transposed activations)   outT: [256][32]
// W: row-major K x 256 in global.  wt: LDS staging tile 16 x 256.
// Thread micro-tile: 4 rows x 8 cols (tid = tr*32+tc; rows tr*4, cols tc*8).
// ---------------------------------------------------------------------------
__device__ __forceinline__ void gemm_relu_256(
    const float* __restrict__ inT, int K,
    const float* __restrict__ W, const float* __restrict__ bias,
    float* __restrict__ outT, float* __restrict__ wt, int tid)
{
    const int tc = tid & 31, tr = tid >> 5;
    const int c0 = tc * 8, r0 = tr * 4;
    float acc[4][8];
#pragma unroll
    for (int j = 0; j < 8; ++j) {
        const float bj = bias[c0 + j];
#pragma unroll
        for (int i = 0; i < 4; ++i) acc[i][j] = bj;
    }
    for (int k0 = 0; k0 < K; k0 += 16) {
#pragma unroll
        for (int t = 0; t < 16; ++t)
            wt[t * 256 + tid] = W[(size_t)(k0 + t) * 256 + tid];
        __syncthreads();
#pragma unroll
        for (int kk = 0; kk < 16; ++kk) {
            const float4 av = *(const float4*)(inT + (k0 + kk) * 32 + r0);
            const float4 wa = *(const float4*)(wt + kk * 256 + c0);
            const float4 wb = *(const float4*)(wt + kk * 256 + c0 + 4);
            const float aa[4] = {av.x, av.y, av.z, av.w};
            const float ww[8] = {wa.x, wa.y, wa.z, wa.w, wb.x, wb.y, wb.z, wb.w};
#pragma unroll
            for (int i = 0; i < 4; ++i)
#pragma unroll
                for (int j = 0; j < 8; ++j)
                    acc[i][j] = fmaf(aa[i], ww[j], acc[i][j]);
        }
        __syncthreads();
    }
#pragma unroll
    for (int j = 0; j < 8; ++j)
#pragma unroll
        for (int i = 0; i < 4; ++i)
            outT[(c0 + j) * 32 + r0 + i] = fmaxf(acc[i][j], 0.f);
    __syncthreads();
}

// ---------------------------------------------------------------------------
// Scorer: for 32 candidates (one WG), compute z, run mu/sig/risk chains,
// emit score.  Grid = B*S/32 = 4096 blocks, 256 threads.
// ---------------------------------------------------------------------------
__global__ __launch_bounds__(256, 2) void score_kernel(
    const float* __restrict__ s0, const float* __restrict__ eps,
    const float* __restrict__ mu_w1, const float* __restrict__ mu_b1,
    const float* __restrict__ mu_w2, const float* __restrict__ mu_b2,
    const float* __restrict__ mu_w3, const float* __restrict__ mu_b3,
    const float* __restrict__ sig_w1, const float* __restrict__ sig_b1,
    const float* __restrict__ sig_w2, const float* __restrict__ sig_b2,
    const float* __restrict__ sig_w3, const float* __restrict__ sig_b3,
    const float* __restrict__ risk_w1, const float* __restrict__ risk_b1,
    const float* __restrict__ risk_w2, const float* __restrict__ risk_b2,
    const float* __restrict__ risk_w3, const float* __restrict__ risk_b3,
    const float* __restrict__ mu, const float* __restrict__ stdv,
    float* __restrict__ score, int iter)
{
    __shared__ __align__(16) float xT[80 * 32];    // [k][r] : x = [s0(64), z(16)]
    __shared__ __align__(16) float hT[256 * 32];   // [c][r] hidden activations
    __shared__ __align__(16) float wt[16 * 256];   // weight staging tile
    __shared__ float w3c0[256], w3c1[256];
    __shared__ float muS[ZD_], stdS[ZD_];
    __shared__ float intentL[32], agencyL[32], riskL[32];

    const int tid  = threadIdx.x;
    const int row0 = blockIdx.x * 32;     // 32 | 512, so whole WG shares one b
    const int b    = row0 >> 9;

    if (tid < ZD_) { muS[tid] = mu[b * ZD_ + tid]; stdS[tid] = stdv[b * ZD_ + tid]; }
    if (tid < OBS_) {
        const float v = s0[b * OBS_ + tid];
#pragma unroll
        for (int r = 0; r < 32; ++r) xT[tid * 32 + r] = v;
    }
    __syncthreads();
    {   // z = mu + std * eps[iter][row]
        const float* epsI = eps + ((size_t)iter * B_ * S_ + row0) * ZD_;
        for (int l = tid; l < 32 * ZD_; l += 256) {
            const int r = l >> 4, d = l & 15;
            xT[(OBS_ + d) * 32 + r] = fmaf(stdS[d], epsI[l], muS[d]);
        }
    }
    __syncthreads();

    const float g0 = xT[2 * 32], g1 = xT[3 * 32];   // goal = s0[:,2:4]

    // ---- mu chain -------------------------------------------------------
    gemm_relu_256(xT, 80, mu_w1, mu_b1, hT, wt, tid);
    gemm_relu_256(hT, 256, mu_w2, mu_b2, hT, wt, tid);

    // intent: only columns 126/127 of mu_w3 are used (mu_out[:,:,-1,:])
    w3c0[tid] = mu_w3[tid * 128 + 126];
    w3c1[tid] = mu_w3[tid * 128 + 127];
    __syncthreads();
    {
        const int r = tid >> 3, l8 = tid & 7;
        float p0 = 0.f, p1 = 0.f;
        for (int t = 0; t < 32; ++t) {
            const int k = l8 * 32 + t;
            const float h = hT[k * 32 + r];
            p0 = fmaf(h, w3c0[k], p0);
            p1 = fmaf(h, w3c1[k], p1);
        }
        p0 += __shfl_xor(p0, 1); p0 += __shfl_xor(p0, 2); p0 += __shfl_xor(p0, 4);
        p1 += __shfl_xor(p1, 1); p1 += __shfl_xor(p1, 2); p1 += __shfl_xor(p1, 4);
        if (l8 == 0) {
            const float m0 = p0 + mu_b3[126], m1 = p1 + mu_b3[127];
            const float d0 = m0 - g0, d1 = m1 - g1;
            intentL[r] = d0 * d0 + d1 * d1;
        }
    }
    __syncthreads();

    // ---- sig chain ------------------------------------------------------
    gemm_relu_256(xT + OBS_ * 32, 16, sig_w1, sig_b1, hT, wt, tid);
    gemm_relu_256(hT, 256, sig_w2, sig_b2, hT, wt, tid);
    {   // layer3: 128 outputs, clip(-4,3), agency = -mean
        const int tc = tid & 31, tr = tid >> 5;
        const int c0 = tc * 4, r0 = tr * 4;
        float acc[4][4];
#pragma unroll
        for (int j = 0; j < 4; ++j) {
            const float bj = sig_b3[c0 + j];
#pragma unroll
            for (int i = 0; i < 4; ++i) acc[i][j] = bj;
        }
        for (int k0 = 0; k0 < 256; k0 += 16) {
#pragma unroll
            for (int t = 0; t < 8; ++t) {
                const int l = t * 256 + tid;
                const int kk = l >> 7, c = l & 127;
                wt[kk * 128 + c] = sig_w3[(size_t)(k0 + kk) * 128 + c];
            }
            __syncthreads();
#pragma unroll
            for (int kk = 0; kk < 16; ++kk) {
                const float4 av = *(const float4*)(hT + (k0 + kk) * 32 + r0);
                const float4 wv = *(const float4*)(wt + kk * 128 + c0);
                const float aa[4] = {av.x, av.y, av.z, av.w};
                const float ww[4] = {wv.x, wv.y, wv.z, wv.w};
#pragma unroll
                for (int i = 0; i < 4; ++i)
#pragma unroll
                    for (int j = 0; j < 4; ++j)
                        acc[i][j] = fmaf(aa[i], ww[j], acc[i][j]);
            }
            __syncthreads();
        }
        float p[4];
#pragma unroll
        for (int i = 0; i < 4; ++i) {
            float s = 0.f;
#pragma unroll
            for (int j = 0; j < 4; ++j)
                s += fminf(fmaxf(acc[i][j], -4.f), 3.f);
            p[i] = s;
        }
#pragma unroll
        for (int m = 1; m < 32; m <<= 1)
#pragma unroll
            for (int i = 0; i < 4; ++i) p[i] += __shfl_xor(p[i], m);
        if (tc == 0)
#pragma unroll
            for (int i = 0; i < 4; ++i) agencyL[r0 + i] = -p[i] * (1.f / 128.f);
    }
    __syncthreads();

    // ---- risk chain -----------------------------------------------------
    gemm_relu_256(xT, 80, risk_w1, risk_b1, hT, wt, tid);
    gemm_relu_256(hT, 256, risk_w2, risk_b2, hT, wt, tid);
    w3c0[tid] = risk_w3[tid];
    __syncthreads();
    {
        const int r = tid >> 3, l8 = tid & 7;
        float p = 0.f;
        for (int t = 0; t < 32; ++t) {
            const int k = l8 * 32 + t;
            p = fmaf(hT[k * 32 + r], w3c0[k], p);
        }
        p += __shfl_xor(p, 1); p += __shfl_xor(p, 2); p += __shfl_xor(p, 4);
        if (l8 == 0) riskL[r] = 1.f / (1.f + expf(-(p + risk_b3[0])));
    }
    __syncthreads();

    if (tid < 32)
        score[row0 + tid] = -intentL[tid] + 0.5f * agencyL[tid] - riskL[tid];
}

// ---------------------------------------------------------------------------
// Per-batch-row CEM update: top-64 of 512 via bitonic sort, elite mean/std
// (ddof=1), mu/std smoothing, best_z/best_score tracking.
// z is recomputed from (pre-update) mu/std and eps.
// ---------------------------------------------------------------------------
__global__ __launch_bounds__(256) void update_kernel(
    const float* __restrict__ score, const float* __restrict__ eps,
    float* __restrict__ mu, float* __restrict__ stdv,
    float* __restrict__ bscore, float* __restrict__ bz, int iter)
{
    __shared__ unsigned long long keys[512];
    __shared__ float ez[64][ZD_];
    __shared__ float mold[ZD_], sold[ZD_];
    __shared__ int flagL, idx0L;

    const int b = blockIdx.x, tid = threadIdx.x;

    for (int l = tid; l < 512; l += 256) {
        const float sc = score[b * 512 + l];
        unsigned int u = __float_as_uint(sc);
        u = (u & 0x80000000u) ? ~u : (u | 0x80000000u);   // order-preserving
        const unsigned long long key =
            ((unsigned long long)u << 32) | (unsigned long long)(511 - l);
        keys[l] = ~key;   // ascending sort of ~key == descending by (score, -idx)
    }
    if (tid < ZD_) { mold[tid] = mu[b * ZD_ + tid]; sold[tid] = stdv[b * ZD_ + tid]; }
    __syncthreads();

    // bitonic sort, 512 elements, 256 threads, ascending
    for (int size = 2; size < 512; size <<= 1) {
        const int ddd = ((tid & (size >> 1)) != 0) ? 0 : 1;
        for (int stride = size >> 1; stride > 0; stride >>= 1) {
            __syncthreads();
            const int pos = 2 * tid - (tid & (stride - 1));
            const unsigned long long a = keys[pos], c = keys[pos + stride];
            if ((a > c) == (ddd != 0)) { keys[pos] = c; keys[pos + stride] = a; }
        }
    }
    for (int stride = 256; stride > 0; stride >>= 1) {
        __syncthreads();
        const int pos = 2 * tid - (tid & (stride - 1));
        const unsigned long long a = keys[pos], c = keys[pos + stride];
        if (a > c) { keys[pos] = c; keys[pos + stride] = a; }
    }
    __syncthreads();

    // gather elite z (recompute from pre-update mu/std)
    const float* epsB = eps + ((size_t)iter * B_ * S_ + (size_t)b * S_) * ZD_;
    for (int l = tid; l < 64 * ZD_; l += 256) {
        const int e = l >> 4, d = l & 15;
        const unsigned long long key = ~keys[e];
        const int idx = 511 - (int)(key & 0xFFFFFFFFull);
        ez[e][d] = fmaf(sold[d], epsB[idx * ZD_ + d], mold[d]);
    }
    __syncthreads();

    if (tid < ZD_) {
        float s = 0.f;
        for (int e = 0; e < 64; ++e) s += ez[e][tid];
        const float mean = s * (1.f / 64.f);
        float v = 0.f;
        for (int e = 0; e < 64; ++e) { const float d = ez[e][tid] - mean; v = fmaf(d, d, v); }
        const float sd = sqrtf(v * (1.f / 63.f));          // ddof=1
        mu[b * ZD_ + tid]   = 0.25f * mold[tid] + 0.75f * mean;
        stdv[b * ZD_ + tid] = fmaxf(0.25f * sold[tid] + 0.75f * sd, 0.2f);
    }
    if (tid == 0) {
        const unsigned long long key = ~keys[0];
        const int idx0 = 511 - (int)(key & 0xFFFFFFFFull);
        const float v = score[b * 512 + idx0];
        const int better = (v > bscore[b]) ? 1 : 0;
        if (better) bscore[b] = v;
        flagL = better; idx0L = idx0;
    }
    __syncthreads();
    if (tid < ZD_ && flagL)
        bz[b * ZD_ + tid] = fmaf(sold[tid], epsB[idx0L * ZD_ + tid], mold[tid]);
}

// ---------------------------------------------------------------------------
// Output: concat([best_z, best_score], -1) -> (B, 17) as f32
// ---------------------------------------------------------------------------
__global__ __launch_bounds__(256) void out_kernel(
    const float* __restrict__ bz, const float* __restrict__ bscore,
    float* __restrict__ out)
{
    const int i = blockIdx.x * 256 + threadIdx.x;
    if (i < B_ * 17) {
        const int b = i / 17, d = i % 17;
        const float v = (d < ZD_) ? bz[b * ZD_ + d] : bscore[b];
        out[i] = v;
    }
}

extern "C" void kernel_launch(void* const* d_in, const int* in_sizes, int n_in,
                              void* d_out, int out_size, void* d_ws, size_t ws_size,
                              hipStream_t stream)
{
    (void)in_sizes; (void)n_in; (void)out_size; (void)ws_size;
    const float* s0      = (const float*)d_in[0];
    const float* eps     = (const float*)d_in[1];
    const float* enc_w1  = (const float*)d_in[2];
    const float* enc_b1  = (const float*)d_in[3];
    const float* enc_w2  = (const float*)d_in[4];
    const float* enc_b2  = (const float*)d_in[5];
    const float* zmu_w   = (const float*)d_in[6];
    const float* zmu_b   = (const float*)d_in[7];
    const float* zls_w   = (const float*)d_in[8];
    const float* zls_b   = (const float*)d_in[9];
    const float* mu_w1   = (const float*)d_in[10];
    const float* mu_b1   = (const float*)d_in[11];
    const float* mu_w2   = (const float*)d_in[12];
    const float* mu_b2   = (const float*)d_in[13];
    const float* mu_w3   = (const float*)d_in[14];
    const float* mu_b3   = (const float*)d_in[15];
    const float* sig_w1  = (const float*)d_in[16];
    const float* sig_b1  = (const float*)d_in[17];
    const float* sig_w2  = (const float*)d_in[18];
    const float* sig_b2  = (const float*)d_in[19];
    const float* sig_w3  = (const float*)d_in[20];
    const float* sig_b3  = (const float*)d_in[21];
    const float* risk_w1 = (const float*)d_in[22];
    const float* risk_b1 = (const float*)d_in[23];
    const float* risk_w2 = (const float*)d_in[24];
    const float* risk_b2 = (const float*)d_in[25];
    const float* risk_w3 = (const float*)d_in[26];
    const float* risk_b3 = (const float*)d_in[27];

    float* ws     = (float*)d_ws;
    float* mu     = ws;                 // 256*16
    float* stdv   = ws + 4096;          // 256*16
    float* bscore = ws + 8192;          // 256
    float* bz     = ws + 8448;          // 256*16
    float* score  = ws + 12544;         // 256*512

    enc_kernel<<<B_, 256, 0, stream>>>(s0, enc_w1, enc_b1, enc_w2, enc_b2,
                                       zmu_w, zmu_b, zls_w, zls_b,
                                       mu, stdv, bscore);
    for (int it = 0; it < ITERS_; ++it) {
        score_kernel<<<(B_ * S_) / 32, 256, 0, stream>>>(
            s0, eps,
            mu_w1, mu_b1, mu_w2, mu_b2, mu_w3, mu_b3,
            sig_w1, sig_b1, sig_w2, sig_b2, sig_w3, sig_b3,
            risk_w1, risk_b1, risk_w2, risk_b2, risk_w3, risk_b3,
            mu, stdv, score, it);
        update_kernel<<<B_, 256, 0, stream>>>(score, eps, mu, stdv, bscore, bz, it);
    }
    out_kernel<<<(B_ * 17 + 255) / 256, 256, 0, stream>>>(bz, bscore,
                                                          (float*)d_out);
}

// Round 4
// 5066.345 us; speedup vs baseline: 1.0349x; 1.0349x over previous
//
#include <hip/hip_runtime.h>

#define B_    256
#define S_    512
#define OBS_  64
#define ZD_   16
#define HID_  256
#define ITERS_ 4
#define RT_   16          // rows per block tile
#define STR_  20          // act LDS stride (floats): 16 rows + 4 pad; 20c mod 32 spreads banks

// ---------------------------------------------------------------------------
// Encoder (unchanged; not a bottleneck)
// ---------------------------------------------------------------------------
__global__ __launch_bounds__(256) void enc_kernel(
    const float* __restrict__ s0,
    const float* __restrict__ w1, const float* __restrict__ b1,
    const float* __restrict__ w2, const float* __restrict__ b2,
    const float* __restrict__ zmw, const float* __restrict__ zmb,
    const float* __restrict__ zlw, const float* __restrict__ zlb,
    float* __restrict__ mu, float* __restrict__ stdv, float* __restrict__ bscore)
{
    __shared__ float s0s[OBS_];
    __shared__ float h1[HID_];
    __shared__ float h2[HID_];
    const int b = blockIdx.x, tid = threadIdx.x;
    if (tid < OBS_) s0s[tid] = s0[b * OBS_ + tid];
    __syncthreads();
    float a = b1[tid];
    for (int k = 0; k < OBS_; ++k) a = fmaf(s0s[k], w1[k * HID_ + tid], a);
    h1[tid] = fmaxf(a, 0.f);
    __syncthreads();
    float a2 = b2[tid];
    for (int k = 0; k < HID_; ++k) a2 = fmaf(h1[k], w2[k * HID_ + tid], a2);
    h2[tid] = fmaxf(a2, 0.f);
    __syncthreads();
    if (tid < ZD_) {
        float m = zmb[tid];
        for (int k = 0; k < HID_; ++k) m = fmaf(h2[k], zmw[k * ZD_ + tid], m);
        mu[b * ZD_ + tid] = m;
    } else if (tid < 2 * ZD_) {
        const int d = tid - ZD_;
        float l = zlb[d];
        for (int k = 0; k < HID_; ++k) l = fmaf(h2[k], zlw[k * ZD_ + d], l);
        l = fminf(fmaxf(l, -4.f), 2.f);
        stdv[b * ZD_ + d] = expf(l);
    } else if (tid == 2 * ZD_) {
        bscore[b] = -INFINITY;
    }
}

// ---------------------------------------------------------------------------
// Column-mapped GEMM + relu: thread owns cols {2*tid, 2*tid+1} x 16 rows.
// inT: [K][STR_] activations ([k][r]); W row-major KxN256 read direct from
// global (L1/L2-resident, coalesced float2/lane); outT: [256][STR_].
// Per k: 1 global dwordx2 + 4 broadcast ds_read_b128 + 32 fmaf. No barriers.
// ---------------------------------------------------------------------------
__device__ __forceinline__ void gemm16(
    const float* __restrict__ inT, int K,
    const float* __restrict__ W, const float* __restrict__ bias,
    float* __restrict__ outT, int tid)
{
    const int c0 = tid * 2;
    const float2 bv = *(const float2*)(bias + c0);
    float acc0[RT_], acc1[RT_];
#pragma unroll
    for (int r = 0; r < RT_; ++r) { acc0[r] = bv.x; acc1[r] = bv.y; }
    const float* wp = W + c0;
#pragma unroll 2
    for (int k = 0; k < K; ++k) {
        const float2 w  = *(const float2*)(wp + (size_t)k * 256);
        const float4 a0 = *(const float4*)(inT + k * STR_);
        const float4 a1 = *(const float4*)(inT + k * STR_ + 4);
        const float4 a2 = *(const float4*)(inT + k * STR_ + 8);
        const float4 a3 = *(const float4*)(inT + k * STR_ + 12);
        const float aa[RT_] = {a0.x,a0.y,a0.z,a0.w, a1.x,a1.y,a1.z,a1.w,
                               a2.x,a2.y,a2.z,a2.w, a3.x,a3.y,a3.z,a3.w};
#pragma unroll
        for (int r = 0; r < RT_; ++r) {
            acc0[r] = fmaf(aa[r], w.x, acc0[r]);
            acc1[r] = fmaf(aa[r], w.y, acc1[r]);
        }
    }
#pragma unroll
    for (int ri = 0; ri < 4; ++ri) {
        float4 o0, o1;
        o0.x = fmaxf(acc0[4*ri+0], 0.f); o0.y = fmaxf(acc0[4*ri+1], 0.f);
        o0.z = fmaxf(acc0[4*ri+2], 0.f); o0.w = fmaxf(acc0[4*ri+3], 0.f);
        o1.x = fmaxf(acc1[4*ri+0], 0.f); o1.y = fmaxf(acc1[4*ri+1], 0.f);
        o1.z = fmaxf(acc1[4*ri+2], 0.f); o1.w = fmaxf(acc1[4*ri+3], 0.f);
        *(float4*)(outT + (size_t)c0 * STR_ + 4*ri)       = o0;
        *(float4*)(outT + (size_t)(c0+1) * STR_ + 4*ri)   = o1;
    }
}

// ---------------------------------------------------------------------------
// Scorer: 16 candidates per block, 128 threads. Grid = B*S/16 = 8192 blocks.
// ---------------------------------------------------------------------------
__global__ __launch_bounds__(128, 2) void score_kernel(
    const float* __restrict__ s0, const float* __restrict__ eps,
    const float* __restrict__ mu_w1, const float* __restrict__ mu_b1,
    const float* __restrict__ mu_w2, const float* __restrict__ mu_b2,
    const float* __restrict__ mu_w3, const float* __restrict__ mu_b3,
    const float* __restrict__ sig_w1, const float* __restrict__ sig_b1,
    const float* __restrict__ sig_w2, const float* __restrict__ sig_b2,
    const float* __restrict__ sig_w3, const float* __restrict__ sig_b3,
    const float* __restrict__ risk_w1, const float* __restrict__ risk_b1,
    const float* __restrict__ risk_w2, const float* __restrict__ risk_b2,
    const float* __restrict__ risk_w3, const float* __restrict__ risk_b3,
    const float* __restrict__ mu, const float* __restrict__ stdv,
    float* __restrict__ score, int iter)
{
    __shared__ __align__(16) float xT[80 * STR_];      // input x: [k][r]
    __shared__ __align__(16) float hA[HID_ * STR_];    // layer-1 out / scratch
    __shared__ __align__(16) float hB[HID_ * STR_];    // layer-2 out
    __shared__ float w3m[2 * HID_];                    // mu_w3 cols 126/127: [k][2]
    __shared__ float rw3[HID_];                        // risk_w3
    __shared__ float red[8][RT_], red2[8][RT_];        // seg-partial reduce
    __shared__ float intentL[RT_], agencyL[RT_], riskL[RT_];
    __shared__ float muS[ZD_], stdS[ZD_];

    const int tid  = threadIdx.x;
    const int row0 = blockIdx.x * RT_;   // 16 | 512 -> whole block shares one b
    const int b    = row0 >> 9;

    if (tid < ZD_) { muS[tid] = mu[b * ZD_ + tid]; stdS[tid] = stdv[b * ZD_ + tid]; }
    if (tid < OBS_) {
        const float v = s0[b * OBS_ + tid];
#pragma unroll
        for (int r = 0; r < RT_; ++r) xT[tid * STR_ + r] = v;
    }
    __syncthreads();
    {   // z = mu + std * eps[iter][row]
        const float* epsI = eps + ((size_t)iter * B_ * S_ + row0) * ZD_;
        for (int l = tid; l < RT_ * ZD_; l += 128) {
            const int r = l & 15, d = l >> 4;
            xT[(OBS_ + d) * STR_ + r] = fmaf(stdS[d], epsI[r * ZD_ + d], muS[d]);
        }
    }
    __syncthreads();

    // ---- mu chain -------------------------------------------------------
    gemm16(xT, 80, mu_w1, mu_b1, hA, tid);  __syncthreads();
    gemm16(hA, 256, mu_w2, mu_b2, hB, tid); __syncthreads();
    {   // stage mu_w3 cols 126/127
        const float2 v1 = *(const float2*)(mu_w3 + (size_t)tid * 128 + 126);
        w3m[2*tid]   = v1.x; w3m[2*tid+1]   = v1.y;
        const float2 v2 = *(const float2*)(mu_w3 + (size_t)(tid+128) * 128 + 126);
        w3m[2*(tid+128)]   = v2.x; w3m[2*(tid+128)+1] = v2.y;
    }
    __syncthreads();
    {   // intent partials: thread (r, seg) over 32 k
        const int r = tid & 15, seg = tid >> 4;
        float p0 = 0.f, p1 = 0.f;
        for (int i = 0; i < 32; ++i) {
            const int k = seg * 32 + i;
            const float h = hB[k * STR_ + r];
            p0 = fmaf(h, w3m[2*k],   p0);
            p1 = fmaf(h, w3m[2*k+1], p1);
        }
        red[seg][r] = p0; red2[seg][r] = p1;
    }
    __syncthreads();
    if (tid < RT_) {
        float m0 = 0.f, m1 = 0.f;
        for (int sg = 0; sg < 8; ++sg) { m0 += red[sg][tid]; m1 += red2[sg][tid]; }
        m0 += mu_b3[126]; m1 += mu_b3[127];
        const float g0 = s0[b * OBS_ + 2], g1 = s0[b * OBS_ + 3];
        const float d0 = m0 - g0, d1 = m1 - g1;
        intentL[tid] = d0 * d0 + d1 * d1;
    }
    __syncthreads();

    // ---- sig chain ------------------------------------------------------
    gemm16(xT + OBS_ * STR_, 16, sig_w1, sig_b1, hA, tid); __syncthreads();
    gemm16(hA, 256, sig_w2, sig_b2, hB, tid);              __syncthreads();
    {   // layer3: thread = col c (128 cols); clip; partials into hA [c][r]
        const int c = tid;
        float acc[RT_];
        const float bc = sig_b3[c];
#pragma unroll
        for (int r = 0; r < RT_; ++r) acc[r] = bc;
        const float* wp = sig_w3 + c;
#pragma unroll 2
        for (int k = 0; k < 256; ++k) {
            const float w  = wp[(size_t)k * 128];
            const float4 a0 = *(const float4*)(hB + k * STR_);
            const float4 a1 = *(const float4*)(hB + k * STR_ + 4);
            const float4 a2 = *(const float4*)(hB + k * STR_ + 8);
            const float4 a3 = *(const float4*)(hB + k * STR_ + 12);
            const float aa[RT_] = {a0.x,a0.y,a0.z,a0.w, a1.x,a1.y,a1.z,a1.w,
                                   a2.x,a2.y,a2.z,a2.w, a3.x,a3.y,a3.z,a3.w};
#pragma unroll
            for (int r = 0; r < RT_; ++r) acc[r] = fmaf(aa[r], w, acc[r]);
        }
#pragma unroll
        for (int ri = 0; ri < 4; ++ri) {
            float4 o;
            o.x = fminf(fmaxf(acc[4*ri+0], -4.f), 3.f);
            o.y = fminf(fmaxf(acc[4*ri+1], -4.f), 3.f);
            o.z = fminf(fmaxf(acc[4*ri+2], -4.f), 3.f);
            o.w = fminf(fmaxf(acc[4*ri+3], -4.f), 3.f);
            *(float4*)(hA + (size_t)c * STR_ + 4*ri) = o;
        }
    }
    __syncthreads();
    {   // row-sum across 128 cols: thread (r, seg) sums 16 cols
        const int r = tid & 15, seg = tid >> 4;
        float s = 0.f;
        for (int i = 0; i < 16; ++i) s += hA[(seg * 16 + i) * STR_ + r];
        red[seg][r] = s;
    }
    __syncthreads();
    if (tid < RT_) {
        float s = 0.f;
        for (int sg = 0; sg < 8; ++sg) s += red[sg][tid];
        agencyL[tid] = -s * (1.f / 128.f);
    }
    __syncthreads();

    // ---- risk chain -----------------------------------------------------
    gemm16(xT, 80, risk_w1, risk_b1, hA, tid);  __syncthreads();
    gemm16(hA, 256, risk_w2, risk_b2, hB, tid); __syncthreads();
    rw3[tid] = risk_w3[tid]; rw3[tid + 128] = risk_w3[tid + 128];
    __syncthreads();
    {
        const int r = tid & 15, seg = tid >> 4;
        float p = 0.f;
        for (int i = 0; i < 32; ++i) {
            const int k = seg * 32 + i;
            p = fmaf(hB[k * STR_ + r], rw3[k], p);
        }
        red[seg][r] = p;
    }
    __syncthreads();
    if (tid < RT_) {
        float p = 0.f;
        for (int sg = 0; sg < 8; ++sg) p += red[sg][tid];
        riskL[tid] = 1.f / (1.f + expf(-(p + risk_b3[0])));
        score[row0 + tid] = -intentL[tid] + 0.5f * agencyL[tid] - riskL[tid];
    }
}

// ---------------------------------------------------------------------------
// Per-batch-row CEM update (unchanged; verified bit-exact)
// ---------------------------------------------------------------------------
__global__ __launch_bounds__(256) void update_kernel(
    const float* __restrict__ score, const float* __restrict__ eps,
    float* __restrict__ mu, float* __restrict__ stdv,
    float* __restrict__ bscore, float* __restrict__ bz, int iter)
{
    __shared__ unsigned long long keys[512];
    __shared__ float ez[64][ZD_];
    __shared__ float mold[ZD_], sold[ZD_];
    __shared__ int flagL, idx0L;

    const int b = blockIdx.x, tid = threadIdx.x;

    for (int l = tid; l < 512; l += 256) {
        const float sc = score[b * 512 + l];
        unsigned int u = __float_as_uint(sc);
        u = (u & 0x80000000u) ? ~u : (u | 0x80000000u);   // order-preserving
        const unsigned long long key =
            ((unsigned long long)u << 32) | (unsigned long long)(511 - l);
        keys[l] = ~key;   // ascending sort of ~key == descending by (score, -idx)
    }
    if (tid < ZD_) { mold[tid] = mu[b * ZD_ + tid]; sold[tid] = stdv[b * ZD_ + tid]; }
    __syncthreads();

    for (int size = 2; size < 512; size <<= 1) {
        const int ddd = ((tid & (size >> 1)) != 0) ? 0 : 1;
        for (int stride = size >> 1; stride > 0; stride >>= 1) {
            __syncthreads();
            const int pos = 2 * tid - (tid & (stride - 1));
            const unsigned long long a = keys[pos], c = keys[pos + stride];
            if ((a > c) == (ddd != 0)) { keys[pos] = c; keys[pos + stride] = a; }
        }
    }
    for (int stride = 256; stride > 0; stride >>= 1) {
        __syncthreads();
        const int pos = 2 * tid - (tid & (stride - 1));
        const unsigned long long a = keys[pos], c = keys[pos + stride];
        if (a > c) { keys[pos] = c; keys[pos + stride] = a; }
    }
    __syncthreads();

    const float* epsB = eps + ((size_t)iter * B_ * S_ + (size_t)b * S_) * ZD_;
    for (int l = tid; l < 64 * ZD_; l += 256) {
        const int e = l >> 4, d = l & 15;
        const unsigned long long key = ~keys[e];
        const int idx = 511 - (int)(key & 0xFFFFFFFFull);
        ez[e][d] = fmaf(sold[d], epsB[idx * ZD_ + d], mold[d]);
    }
    __syncthreads();

    if (tid < ZD_) {
        float s = 0.f;
        for (int e = 0; e < 64; ++e) s += ez[e][tid];
        const float mean = s * (1.f / 64.f);
        float v = 0.f;
        for (int e = 0; e < 64; ++e) { const float d = ez[e][tid] - mean; v = fmaf(d, d, v); }
        const float sd = sqrtf(v * (1.f / 63.f));          // ddof=1
        mu[b * ZD_ + tid]   = 0.25f * mold[tid] + 0.75f * mean;
        stdv[b * ZD_ + tid] = fmaxf(0.25f * sold[tid] + 0.75f * sd, 0.2f);
    }
    if (tid == 0) {
        const unsigned long long key = ~keys[0];
        const int idx0 = 511 - (int)(key & 0xFFFFFFFFull);
        const float v = score[b * 512 + idx0];
        const int better = (v > bscore[b]) ? 1 : 0;
        if (better) bscore[b] = v;
        flagL = better; idx0L = idx0;
    }
    __syncthreads();
    if (tid < ZD_ && flagL)
        bz[b * ZD_ + tid] = fmaf(sold[tid], epsB[idx0L * ZD_ + tid], mold[tid]);
}

__global__ __launch_bounds__(256) void out_kernel(
    const float* __restrict__ bz, const float* __restrict__ bscore,
    float* __restrict__ out)
{
    const int i = blockIdx.x * 256 + threadIdx.x;
    if (i < B_ * 17) {
        const int b = i / 17, d = i % 17;
        out[i] = (d < ZD_) ? bz[b * ZD_ + d] : bscore[b];
    }
}

extern "C" void kernel_launch(void* const* d_in, const int* in_sizes, int n_in,
                              void* d_out, int out_size, void* d_ws, size_t ws_size,
                              hipStream_t stream)
{
    (void)in_sizes; (void)n_in; (void)out_size; (void)ws_size;
    const float* s0      = (const float*)d_in[0];
    const float* eps     = (const float*)d_in[1];
    const float* enc_w1  = (const float*)d_in[2];
    const float* enc_b1  = (const float*)d_in[3];
    const float* enc_w2  = (const float*)d_in[4];
    const float* enc_b2  = (const float*)d_in[5];
    const float* zmu_w   = (const float*)d_in[6];
    const float* zmu_b   = (const float*)d_in[7];
    const float* zls_w   = (const float*)d_in[8];
    const float* zls_b   = (const float*)d_in[9];
    const float* mu_w1   = (const float*)d_in[10];
    const float* mu_b1   = (const float*)d_in[11];
    const float* mu_w2   = (const float*)d_in[12];
    const float* mu_b2   = (const float*)d_in[13];
    const float* mu_w3   = (const float*)d_in[14];
    const float* mu_b3   = (const float*)d_in[15];
    const float* sig_w1  = (const float*)d_in[16];
    const float* sig_b1  = (const float*)d_in[17];
    const float* sig_w2  = (const float*)d_in[18];
    const float* sig_b2  = (const float*)d_in[19];
    const float* sig_w3  = (const float*)d_in[20];
    const float* sig_b3  = (const float*)d_in[21];
    const float* risk_w1 = (const float*)d_in[22];
    const float* risk_b1 = (const float*)d_in[23];
    const float* risk_w2 = (const float*)d_in[24];
    const float* risk_b2 = (const float*)d_in[25];
    const float* risk_w3 = (const float*)d_in[26];
    const float* risk_b3 = (const float*)d_in[27];

    float* ws     = (float*)d_ws;
    float* mu     = ws;                 // 256*16
    float* stdv   = ws + 4096;          // 256*16
    float* bscore = ws + 8192;          // 256
    float* bz     = ws + 8448;          // 256*16
    float* score  = ws + 12544;         // 256*512

    enc_kernel<<<B_, 256, 0, stream>>>(s0, enc_w1, enc_b1, enc_w2, enc_b2,
                                       zmu_w, zmu_b, zls_w, zls_b,
                                       mu, stdv, bscore);
    for (int it = 0; it < ITERS_; ++it) {
        score_kernel<<<(B_ * S_) / RT_, 128, 0, stream>>>(
            s0, eps,
            mu_w1, mu_b1, mu_w2, mu_b2, mu_w3, mu_b3,
            sig_w1, sig_b1, sig_w2, sig_b2, sig_w3, sig_b3,
            risk_w1, risk_b1, risk_w2, risk_b2, risk_w3, risk_b3,
            mu, stdv, score, it);
        update_kernel<<<B_, 256, 0, stream>>>(score, eps, mu, stdv, bscore, bz, it);
    }
    out_kernel<<<(B_ * 17 + 255) / 256, 256, 0, stream>>>(bz, bscore,
                                                          (float*)d_out);
}